// Round 7
// baseline (446.425 us; speedup 1.0000x reference)
//
#include <hip/hip_runtime.h>
#include <hip/hip_bf16.h>
#include <stdint.h>

// B=32, S=2048, DK=DV=64, fp32 in/out. out = [output (B,S,64) | attn (B,S,S)].
// Barrier-free per-wave two-phase MFMA attention:
//   prepass: detect mask dtype; fused {K->bf16, V->Vt bf16, mask bit-pack}.
//   main: 64-thread blocks (1 wave), private 8KB LDS, global_load_lds dbuf
//   with counted inline-asm vmcnt (no __syncthreads anywhere).
//   phase 1: 64 x 32-key K tiles -> QK^T=mfma(K,Q), masked exp row-sums.
//   phase 2: 128 x 16-key K+V tiles -> scores recomputed; exp output layout
//   IS the PV A-fragment (zero-shuffle); attn stores buffered 4 tiles and
//   burst-written; PV via zero-padded K=32 MFMA.
// r7 fix: phase-2 first-group wait was vmcnt(8) with only 8 ops outstanding
// (no prior store burst) -> tile-0 race. Now g==0,j==0 uses vmcnt(4).

#define B_ 32
#define S_ 2048
#define D_ 64

typedef float  f32x4  __attribute__((ext_vector_type(4)));
typedef __bf16 bf16x8 __attribute__((ext_vector_type(8)));
typedef __bf16 bf16x4 __attribute__((ext_vector_type(4)));
typedef unsigned short u16x4 __attribute__((ext_vector_type(4)));

#define WAITV(N) do { asm volatile("s_waitcnt vmcnt(" N ")" ::: "memory"); \
                      __builtin_amdgcn_sched_barrier(0); } while (0)
#define WAITL()  do { asm volatile("s_waitcnt lgkmcnt(0)" ::: "memory");   \
                      __builtin_amdgcn_sched_barrier(0); } while (0)

__device__ __forceinline__ unsigned short f2bf(float f) {
  unsigned u = __float_as_uint(f);
  u = (u + 0x7FFFu + ((u >> 16) & 1u)) >> 16;   // RNE
  return (unsigned short)u;
}

__device__ __forceinline__ void load_lds16(const void* g, void* l) {
  __builtin_amdgcn_global_load_lds(
      (const __attribute__((address_space(1))) unsigned*)g,
      (__attribute__((address_space(3))) unsigned*)l, 16, 0, 0);
}

// ---------------- mask dtype detection ----------------
__global__ void detect_mask(const unsigned* __restrict__ m, int* __restrict__ flag) {
  if (threadIdx.x == 0 && blockIdx.x == 0) {
    int wide = 1;
    for (int i = 0; i < 64; ++i) {
      unsigned w = m[i];
      wide &= (w <= 1u || w == 0x3F800000u);
    }
    *flag = wide ? 1 : 0;
  }
}

// ---------------- fused prepass: cast K, transpose V, pack mask ----------
__global__ __launch_bounds__(256) void prep_fused(
    const float* __restrict__ K, unsigned short* __restrict__ Kbf,
    const float* __restrict__ V, unsigned short* __restrict__ Vt,
    const void* __restrict__ M, const int* __restrict__ flag,
    unsigned* __restrict__ Mp) {
  __shared__ float tile[32][33];
  const int bid = blockIdx.x, tid = threadIdx.x;

  if (bid < 4096) {                       // ---- K fp32 -> bf16 ----
    size_t i = ((size_t)bid * 256 + tid) * 4;
    f32x4 v = *reinterpret_cast<const f32x4*>(K + i);
    u16x4 o;
    o[0] = f2bf(v[0]); o[1] = f2bf(v[1]); o[2] = f2bf(v[2]); o[3] = f2bf(v[3]);
    *reinterpret_cast<u16x4*>(Kbf + i) = o;
  } else if (bid < 8192) {                // ---- V -> Vt (d-major) bf16 ----
    int b2 = bid - 4096;
    int k0 = (b2 & 63) * 32, d0 = ((b2 >> 6) & 1) * 32, b = b2 >> 7;
    int tx = tid & 31, ty = tid >> 5;
    const float* src = V + ((size_t)b * S_ + k0) * D_ + d0;
    for (int r = 0; r < 4; ++r) {
      int yy = ty + r * 8;
      tile[yy][tx] = src[(size_t)yy * D_ + tx];
    }
    __syncthreads();
    unsigned short* dst = Vt + ((size_t)b * D_ + d0) * S_ + k0;
    for (int r = 0; r < 4; ++r) {
      int yy = ty + r * 8;
      dst[(size_t)yy * S_ + tx] = f2bf(tile[tx][yy]);
    }
  } else {                                // ---- mask bit-pack ----
    size_t t = (size_t)(bid - 8192) * 256 + tid;
    unsigned bits = 0;
    if (*flag == 0) {
      const uint4* p = (const uint4*)((const uint8_t*)M + t * 32);
      uint4 a = p[0], b = p[1];
      unsigned w[8] = {a.x, a.y, a.z, a.w, b.x, b.y, b.z, b.w};
#pragma unroll
      for (int i = 0; i < 8; ++i)
#pragma unroll
        for (int j = 0; j < 4; ++j)
          bits |= (unsigned)(((w[i] >> (8 * j)) & 0xFFu) != 0u) << (i * 4 + j);
    } else {
      const uint4* p = (const uint4*)((const unsigned*)M + t * 32);
#pragma unroll
      for (int i = 0; i < 8; ++i) {
        uint4 a = p[i];
        bits |= (unsigned)(a.x != 0u) << (i * 4 + 0);
        bits |= (unsigned)(a.y != 0u) << (i * 4 + 1);
        bits |= (unsigned)(a.z != 0u) << (i * 4 + 2);
        bits |= (unsigned)(a.w != 0u) << (i * 4 + 3);
      }
    }
    Mp[t] = bits;
  }
}

// ---------------- main attention ----------------
#define MFMA16(A, B, C) __builtin_amdgcn_mfma_f32_16x16x32_bf16(A, B, C, 0, 0, 0)

__global__ __launch_bounds__(64) void attn_main7(
    const float* __restrict__ Q, const unsigned short* __restrict__ Kbf,
    const unsigned* __restrict__ Mp, const unsigned short* __restrict__ Vt,
    float* __restrict__ Out) {
  // 8 KB LDS, one wave per block, no barriers.
  // phase 1: K dbuf [0,2048),[2048,4096) shorts (32-key tiles, 4 KB each)
  // phase 2: K dbuf [0,1024),[1024,2048); V dbuf [2048,3072),[3072,4096)
  __shared__ __align__(16) unsigned short smem[4096];

  const int wg = blockIdx.x;                  // 4096 wgs (1 wave each)
  const int vdx = (wg & 7) * 512 + (wg >> 3); // XCD-contiguous remap (bijective)
  const int b = vdx >> 7, qt = vdx & 127;
  const int q0 = qt * 16;
  const int lane = threadIdx.x;
  const int lo = lane & 15, hi = lane >> 4;   // hi in [0,4)
  const int sw = lo & 7;

  const unsigned short* Kb  = Kbf + (size_t)b * S_ * D_;
  const unsigned short* Vtb = Vt  + (size_t)b * D_ * S_;
  const unsigned* mptr = Mp + ((size_t)b * S_ + q0 + lo) * (S_ / 32);
  float* outO = Out + (size_t)b * S_ * D_;
  float* sp   = Out + (size_t)B_ * S_ * D_ + ((size_t)b * S_ + q0 + lo) * S_;

  // Q B-fragments (temperature folded, /8 exact): col=query=lo,
  // k-elem j of half kb = d = kb*32 + hi*8 + j
  bf16x8 bq0, bq1;
  {
    const float* qr = Q + ((size_t)b * S_ + q0 + lo) * D_ + hi * 8;
    f32x4 x0 = *reinterpret_cast<const f32x4*>(qr);
    f32x4 y0 = *reinterpret_cast<const f32x4*>(qr + 4);
    f32x4 x1 = *reinterpret_cast<const f32x4*>(qr + 32);
    f32x4 y1 = *reinterpret_cast<const f32x4*>(qr + 36);
#pragma unroll
    for (int j = 0; j < 4; ++j) {
      bq0[j] = (__bf16)(x0[j] * 0.125f); bq0[j + 4] = (__bf16)(y0[j] * 0.125f);
      bq1[j] = (__bf16)(x1[j] * 0.125f); bq1[j + 4] = (__bf16)(y1[j] * 0.125f);
    }
  }

  // staging source offsets (inverse-swizzled, shared by both phases):
  // K: lane l covers row (l>>3) within an 8-row stripe, 16B-slot (l&7)^(l>>3)
  const int krow = lane >> 3;                    // [0,8)
  const int kcol = ((lane & 7) ^ krow) << 3;     // elem offset
  // V: lane l covers d-row (l>>1), 16B-slot (l&1) (no swizzle needed)
  const int vrow = lane >> 1;                    // [0,32)
  const int vcol = (lane & 1) << 3;              // elem offset

  // fragment read offsets (elems):
  const int offK0 = ((hi ^ sw) << 3);
  const int offK1 = (((hi + 4) ^ sw) << 3);

  // ================= phase 1: denominators (64 x 32-key tiles) ==========
  float lsum = 0.f;

#define STAGE_K1(t_, buf_)                                                  \
  {                                                                         \
    const unsigned short* s_ = Kb + (size_t)((t_) * 32 + krow) * D_ + kcol; \
    unsigned short* d_ = &smem[(buf_) * 2048];                              \
    load_lds16(s_,                d_);                                      \
    load_lds16(s_ +  8 * D_,      d_ +  512);                               \
    load_lds16(s_ + 16 * D_,      d_ + 1024);                               \
    load_lds16(s_ + 24 * D_,      d_ + 1536);                               \
  }

#define COMP32(t_, buf_)                                                    \
  {                                                                         \
    const unsigned short* kl = &smem[(buf_) * 2048];                        \
    unsigned mw = mptr[(t_)];                                               \
    _Pragma("unroll")                                                       \
    for (int h = 0; h < 2; ++h) {                                           \
      const unsigned short* kr = kl + (h * 16 + lo) * 64;                   \
      bf16x8 A0 = *reinterpret_cast<const bf16x8*>(kr + offK0);             \
      bf16x8 A1 = *reinterpret_cast<const bf16x8*>(kr + offK1);             \
      f32x4 acc = {0.f, 0.f, 0.f, 0.f};                                     \
      acc = MFMA16(A0, bq0, acc);                                           \
      acc = MFMA16(A1, bq1, acc);                                           \
      unsigned bits = mw >> (h * 16);                                       \
      _Pragma("unroll")                                                     \
      for (int i = 0; i < 4; ++i)                                           \
        lsum += ((bits >> (4 * hi + i)) & 1u) ? 0.f : __expf(acc[i]);       \
    }                                                                       \
  }

  STAGE_K1(0, 0);
  for (int t = 0; t < 63; ++t) {
    STAGE_K1(t + 1, (t + 1) & 1);
    WAITV("4");
    COMP32(t, t & 1);
  }
  WAITV("0");
  COMP32(63, 1);

  lsum += __shfl_xor(lsum, 16, 64);
  lsum += __shfl_xor(lsum, 32, 64);
  const float rinv = 1.0f / lsum;

  // ================= phase 2: attn write + PV (128 x 16-key tiles) ======
  f32x4 oacc[4];
#pragma unroll
  for (int db = 0; db < 4; ++db) {
    oacc[db][0] = 0.f; oacc[db][1] = 0.f; oacc[db][2] = 0.f; oacc[db][3] = 0.f;
  }

#define STAGE_KV2(u_, buf_)                                                 \
  {                                                                         \
    const unsigned short* ks = Kb + (size_t)((u_) * 16 + krow) * D_ + kcol; \
    unsigned short* kd = &smem[(buf_) * 1024];                              \
    load_lds16(ks,           kd);                                           \
    load_lds16(ks + 8 * D_,  kd + 512);                                     \
    const unsigned short* vs = Vtb + (size_t)vrow * S_ + (u_) * 16 + vcol;  \
    unsigned short* vd = &smem[2048 + (buf_) * 1024];                       \
    load_lds16(vs,            vd);                                          \
    load_lds16(vs + 32 * S_,  vd + 512);                                    \
  }

  const bf16x4 zed = {(__bf16)0.f, (__bf16)0.f, (__bf16)0.f, (__bf16)0.f};

  WAITL();               // phase-1 LDS reads done before overwrite
  STAGE_KV2(0, 0);

  for (int g = 0; g < 32; ++g) {
    f32x4 pb0, pb1, pb2, pb3;
#pragma unroll
    for (int j = 0; j < 4; ++j) {
      const int u = g * 4 + j;
      if (u < 127) STAGE_KV2(u + 1, (u + 1) & 1);
      // vmcnt bookkeeping (FIFO, oldest retired first):
      //  steady j==0: [stage(u)(4), stores(4), stage(u+1)(4)] -> wait(8)
      //  g==0,j==0:   [stage(0)(4), stage(1)(4)]              -> wait(4)
      //  j>=1:        [stores?(4), stage(u)(4), stage(u+1)(4)] -> wait(4)
      //  u==127:      drain all                                -> wait(0)
      if (u == 127)      { WAITV("0"); }
      else if (j != 0)   { WAITV("4"); }
      else if (g == 0)   { WAITV("4"); }
      else               { WAITV("8"); }

      const unsigned short* kl = &smem[(u & 1) * 1024];
      const unsigned short* vl = &smem[2048 + (u & 1) * 1024];

      // QK^T for 16 keys: A rows = keys = lo, k = d
      const unsigned short* kr = kl + lo * 64;
      bf16x8 A0 = *reinterpret_cast<const bf16x8*>(kr + offK0);
      bf16x8 A1 = *reinterpret_cast<const bf16x8*>(kr + offK1);
      f32x4 acc = {0.f, 0.f, 0.f, 0.f};
      acc = MFMA16(A0, bq0, acc);
      acc = MFMA16(A1, bq1, acc);

      unsigned mword = mptr[u >> 1];
      unsigned bits = (u & 1) ? (mword >> 16) : (mword & 0xFFFFu);
      f32x4 p;
#pragma unroll
      for (int i = 0; i < 4; ++i)
        p[i] = ((bits >> (4 * hi + i)) & 1u) ? 0.f : __expf(acc[i]) * rinv;

      if (j == 0) pb0 = p; else if (j == 1) pb1 = p;
      else if (j == 2) pb2 = p; else pb3 = p;

      // PV: exp output IS the A-fragment (keys 4hi+i of query lo),
      // zero-padded to K=32. B = Vt fragment from LDS, same key mapping.
      bf16x4 pc;
#pragma unroll
      for (int i = 0; i < 4; ++i) pc[i] = (__bf16)p[i];
      bf16x8 pa = __builtin_shufflevector(pc, zed, 0, 1, 2, 3, 4, 5, 6, 7);
#pragma unroll
      for (int db = 0; db < 4; ++db) {
        bf16x4 vv = *reinterpret_cast<const bf16x4*>(
            vl + (db * 16 + lo) * 16 + hi * 4);
        bf16x8 bv = __builtin_shufflevector(vv, zed, 0, 1, 2, 3, 4, 5, 6, 7);
        oacc[db] = MFMA16(pa, bv, oacc[db]);
      }
    }
    // burst attn stores for the 4 tiles of this group
    float* spg = sp + g * 64 + 4 * hi;
    __builtin_nontemporal_store(pb0, reinterpret_cast<f32x4*>(spg));
    __builtin_nontemporal_store(pb1, reinterpret_cast<f32x4*>(spg + 16));
    __builtin_nontemporal_store(pb2, reinterpret_cast<f32x4*>(spg + 32));
    __builtin_nontemporal_store(pb3, reinterpret_cast<f32x4*>(spg + 48));
  }

  // epilogue: O store. D row = query = 4hi+i, col = d = db*16+lo
#pragma unroll
  for (int db = 0; db < 4; ++db)
#pragma unroll
    for (int i = 0; i < 4; ++i)
      __builtin_nontemporal_store(oacc[db][i],
          outO + (size_t)(q0 + 4 * hi + i) * D_ + db * 16 + lo);
}

extern "C" void kernel_launch(void* const* d_in, const int* in_sizes, int n_in,
                              void* d_out, int out_size, void* d_ws, size_t ws_size,
                              hipStream_t stream) {
  const float* q = (const float*)d_in[0];
  const float* k = (const float*)d_in[1];
  const float* v = (const float*)d_in[2];
  const void*  m = d_in[3];
  float* out = (float*)d_out;

  // ws: [0] flag; [256] Vt bf16 (8MB); [+8MB] Kbf bf16 (8MB); [+8MB] Mp (16MB)
  int* flag = (int*)d_ws;
  unsigned short* Vt  = (unsigned short*)((char*)d_ws + 256);
  unsigned short* Kbf = (unsigned short*)((char*)d_ws + 256 + (size_t)B_ * D_ * S_ * 2);
  unsigned*       Mp  = (unsigned*)((char*)d_ws + 256 + (size_t)B_ * D_ * S_ * 4);

  detect_mask<<<1, 64, 0, stream>>>((const unsigned*)m, flag);
  prep_fused<<<24576, 256, 0, stream>>>(k, Kbf, v, Vt, m, flag, Mp);
  attn_main7<<<B_ * (S_ / 16), 64, 0, stream>>>(q, Kbf, Mp, Vt, out);
}